// Round 2
// baseline (425.082 us; speedup 1.0000x reference)
//
#include <hip/hip_runtime.h>

#define NN 51
#define DD 128
#define RS 132
#define NT 64

// JAX threefry2x32 (20 rounds), exact.
__device__ __forceinline__ void tf2x32(unsigned k0, unsigned k1, unsigned &x0, unsigned &x1) {
  const unsigned ks2 = k0 ^ k1 ^ 0x1BD11BDAu;
  const unsigned ka[5] = {k1, ks2, k0, k1, ks2};
  const unsigned kb[5] = {ks2 + 1u, k0 + 2u, k1 + 3u, ks2 + 4u, k0 + 5u};
  x0 += k0; x1 += k1;
#pragma unroll
  for (int g = 0; g < 5; ++g) {
    const int r0 = (g & 1) ? 17 : 13;
    const int r1 = (g & 1) ? 29 : 15;
    const int r2 = (g & 1) ? 16 : 26;
    const int r3 = (g & 1) ? 24 : 6;
    x0 += x1; x1 = (x1 << r0) | (x1 >> (32 - r0)); x1 ^= x0;
    x0 += x1; x1 = (x1 << r1) | (x1 >> (32 - r1)); x1 ^= x0;
    x0 += x1; x1 = (x1 << r2) | (x1 >> (32 - r2)); x1 ^= x0;
    x0 += x1; x1 = (x1 << r3) | (x1 >> (32 - r3)); x1 ^= x0;
    x0 += ka[g]; x1 += kb[g];
  }
}

// Fully self-contained: no workspace, one block per batch row.
__global__ __launch_bounds__(256, 1) void decode_kernel(
    const float* __restrict__ enc, const float* __restrict__ pool_in,
    const float* __restrict__ cap_p, const float* __restrict__ demand,
    const float* __restrict__ fc_w, const float* __restrict__ fc1,
    const float* __restrict__ wq, const float* __restrict__ wk,
    const float* __restrict__ wv, const float* __restrict__ wo,
    const float* __restrict__ wkp, const float* __restrict__ T_p,
    const int* __restrict__ ns_p, const int* __restrict__ greedy_p,
    float* __restrict__ out) {
  __shared__ __align__(16) float Ksh[NN * RS];
  __shared__ __align__(16) float Vsh[NN * RS];
  __shared__ __align__(16) float KP2sh[NN * RS];   // holds T2=E@wkp, then KP2=T2@wo^T
  __shared__ __align__(16) float EQsh[NN * RS];    // holds T1=E@fc_top, then EQ=T1@wq
  __shared__ __align__(16) float qpoolL[NT * DD];  // phase A: staged enc; later: qpool[t]
  __shared__ __align__(16) float uL[8 * 52];
  __shared__ __align__(16) float qL[DD];
  __shared__ __align__(16) float gL[DD];
  __shared__ __align__(16) float poolL[DD];
  __shared__ __align__(16) float wrowL[DD];
  __shared__ __align__(16) float partF[256];
  __shared__ __align__(16) float partQ[256];
  __shared__ float logitsL[NN], pertL[NN], maskL[NN], mask1L[NN], demL[NN];
  __shared__ unsigned keysL[2 * NT];
  __shared__ float dynL, lpaccL, depotS, lpS;
  __shared__ int idxL, bestS;

  const int b = blockIdx.x, tid = threadIdx.x;
  const int Bn = gridDim.x;
  int ns = *ns_p; if (ns > NT) ns = NT;
  const int greedy = *greedy_p;
  const float Tval = *T_p;
  const float cap0 = *cap_p;
  const float NINF = -__builtin_inff();

  // ---- stage: enc row -> qpoolL (as Etmp, stride DD), demand, pool, state ----
  for (int e = tid; e < NN * DD; e += 256)
    qpoolL[e] = enc[b * NN * DD + e];
  if (tid < 128) poolL[tid] = pool_in[b * DD + tid];
  if (tid < NN)  { demL[tid] = demand[b * NN + tid]; mask1L[tid] = 0.f; }
  if (tid == 0)  { dynL = cap0; lpaccL = 0.f; idxL = 0; }
  // keys: fold_in(key(1234), 0) then partitionable split child t = TF(K,(0,t))
  if (tid < ns) {
    unsigned a0 = 0u, a1 = 0u;
    tf2x32(0u, 1234u, a0, a1);
    unsigned x0 = 0u, x1 = (unsigned)tid;
    tf2x32(a0, a1, x0, x1);
    keysL[2 * tid] = x0; keysL[2 * tid + 1] = x1;
  }
  // wrow[c] = fc_w[128,:] @ wq[:,c]
  if (tid < 128) {
    float s = 0.f;
    for (int j = 0; j < DD; ++j) s += fc_w[128 * DD + j] * wq[j * DD + tid];
    wrowL[tid] = s;
  }
  __syncthreads();

  const int g = tid >> 7, cc = tid & 127;
  const int n0 = g ? 26 : 0, cnt = g ? 25 : 26;

  // ---- phase A: K=E@wk, V=E@wv, T1=E@fc_top, T2=E@wkp (E staged in qpoolL) ----
  {
    const float* Wm[4] = {wk, wv, fc_w, wkp};
    float* Om[4] = {Ksh, Vsh, EQsh, KP2sh};
#pragma unroll
    for (int m = 0; m < 4; ++m) {
      const float* W = Wm[m];
      float acc[26];
#pragma unroll
      for (int r = 0; r < 26; ++r) acc[r] = 0.f;
      for (int i = 0; i < DD; i += 4) {
        const float w0 = W[(i + 0) * DD + cc];
        const float w1 = W[(i + 1) * DD + cc];
        const float w2 = W[(i + 2) * DD + cc];
        const float w3 = W[(i + 3) * DD + cc];
#pragma unroll
        for (int r = 0; r < 26; ++r) {
          if (r < cnt) {
            const float4 e4 = *(const float4*)&qpoolL[(n0 + r) * DD + i];
            acc[r] += e4.x * w0 + e4.y * w1 + e4.z * w2 + e4.w * w3;
          }
        }
      }
      float* O = Om[m];
#pragma unroll
      for (int r = 0; r < 26; ++r) if (r < cnt) O[(n0 + r) * RS + cc] = acc[r];
    }
  }
  __syncthreads();

  // ---- phase B1: EQ = T1 @ wq, in place (read all -> barrier -> write) ----
  {
    float acc[26];
#pragma unroll
    for (int r = 0; r < 26; ++r) acc[r] = 0.f;
    for (int i = 0; i < DD; i += 4) {
      const float w0 = wq[(i + 0) * DD + cc];
      const float w1 = wq[(i + 1) * DD + cc];
      const float w2 = wq[(i + 2) * DD + cc];
      const float w3 = wq[(i + 3) * DD + cc];
#pragma unroll
      for (int r = 0; r < 26; ++r) {
        if (r < cnt) {
          const float4 e4 = *(const float4*)&EQsh[(n0 + r) * RS + i];
          acc[r] += e4.x * w0 + e4.y * w1 + e4.z * w2 + e4.w * w3;
        }
      }
    }
    __syncthreads();
#pragma unroll
    for (int r = 0; r < 26; ++r) if (r < cnt) EQsh[(n0 + r) * RS + cc] = acc[r];
  }
  __syncthreads();

  // ---- phase B2: KP2 = T2 @ wo^T, in place ----
  {
    float acc[26];
#pragma unroll
    for (int r = 0; r < 26; ++r) acc[r] = 0.f;
    for (int d = 0; d < DD; d += 4) {
      const float4 w4 = *(const float4*)&wo[cc * DD + d];
#pragma unroll
      for (int r = 0; r < 26; ++r) {
        if (r < cnt) {
          const float4 t4 = *(const float4*)&KP2sh[(n0 + r) * RS + d];
          acc[r] += t4.x * w4.x + t4.y * w4.y + t4.z * w4.z + t4.w * w4.w;
        }
      }
    }
    __syncthreads();
#pragma unroll
    for (int r = 0; r < 26; ++r) if (r < cnt) KP2sh[(n0 + r) * RS + cc] = acc[r];
  }
  __syncthreads();

  // ---- phase C: pool chain + qpool[t] = pool_{t+1} @ wq, weights in registers ----
  {
    const int i0 = g << 6;
    float wf[64], wqr[64];
#pragma unroll
    for (int i = 0; i < 64; ++i) {
      wf[i]  = fc1[(i0 + i) * DD + cc];
      wqr[i] = wq[(i0 + i) * DD + cc];
    }
    for (int t = 0; t < ns; ++t) {
      float sf = 0.f;
#pragma unroll
      for (int i = 0; i < 64; ++i) sf += poolL[i0 + i] * wf[i];
      partF[tid] = sf;
      __syncthreads();
      if (tid < 128) poolL[tid] = partF[tid] + partF[tid + 128];
      __syncthreads();
      float sq = 0.f;
#pragma unroll
      for (int i = 0; i < 64; ++i) sq += poolL[i0 + i] * wqr[i];
      partQ[tid] = sq;
      __syncthreads();
      if (tid < 128) qpoolL[t * DD + tid] = partQ[tid] + partQ[tid + 128];
      __syncthreads();
    }
  }

  // ---- initial _update_mask(idx=0, dyn=cap0) ----
  if (tid == 0) {
    mask1L[0] = 1.f;
    float s1 = 0.f;
    for (int n = 1; n < NN; ++n) s1 += mask1L[n];
    float depot = 1.f;
    if (s1 >= (float)(NN - 1)) depot = 0.f;
    mask1L[0] = depot;
    depotS = depot;
  }
  __syncthreads();
  if (tid < NN)
    maskL[tid] = (tid == 0) ? depotS
               : fminf(mask1L[tid] + ((demL[tid] > dynL) ? 1.f : 0.f), 1.f);
  __syncthreads();

  // ---- sequential decode (pure LDS, 8 barriers/step) ----
  for (int t = 0; t < ns; ++t) {
    if (tid < 128)
      qL[tid] = EQsh[idxL * RS + tid] + dynL * wrowL[tid] + qpoolL[t * DD + tid];
    __syncthreads();
    // P1: u[h][n] = 0.25 * q_h . K[n]_h, masked
    for (int p = tid; p < 8 * NN; p += 256) {
      const int h = p & 7, n = p >> 3;
      const float4* kr = (const float4*)&Ksh[n * RS + h * 16];
      const float4* qr = (const float4*)&qL[h * 16];
      float s = 0.f;
#pragma unroll
      for (int i = 0; i < 4; ++i) {
        const float4 kk = kr[i], qq = qr[i];
        s += kk.x * qq.x + kk.y * qq.y + kk.z * qq.z + kk.w * qq.w;
      }
      uL[h * 52 + n] = (maskL[n] > 0.f) ? NINF : 0.25f * s;
    }
    __syncthreads();
    // P2: softmax per head (8 heads x 32 lanes)
    {
      const int h = tid >> 5, j = tid & 31;
      float m = NINF;
      for (int n = j; n < NN; n += 32) m = fmaxf(m, uL[h * 52 + n]);
#pragma unroll
      for (int o = 16; o; o >>= 1) m = fmaxf(m, __shfl_xor(m, o, 32));
      float ss = 0.f;
      for (int n = j; n < NN; n += 32) {
        const float e = expf(uL[h * 52 + n] - m);
        uL[h * 52 + n] = e; ss += e;
      }
#pragma unroll
      for (int o = 16; o; o >>= 1) ss += __shfl_xor(ss, o, 32);
      for (int n = j; n < NN; n += 32) uL[h * 52 + n] = uL[h * 52 + n] / ss;
    }
    __syncthreads();
    // P3: g_pre[d] = sum_n a[h(d)][n] * V[n][d]
    if (tid < 128) {
      const int h = tid >> 4;
      float s = 0.f;
      for (int n = 0; n < NN; ++n) s += uL[h * 52 + n] * Vsh[n * RS + tid];
      gL[tid] = s;
    }
    __syncthreads();
    // P4: comp -> logits -> gumbel perturbation
    if (tid < NN) {
      const float4* kp = (const float4*)&KP2sh[tid * RS];
      const float4* gg = (const float4*)gL;
      float s = 0.f;
#pragma unroll 8
      for (int i = 0; i < 32; ++i) {
        const float4 a = kp[i], c4 = gg[i];
        s += a.x * c4.x + a.y * c4.y + a.z * c4.z + a.w * c4.w;
      }
      const float comp = s * 0.08838834764831845f;  // 128^-0.5
      float lg = (10.f * tanhf(comp)) / Tval;
      lg = (maskL[tid] > 0.f) ? NINF : lg;
      logitsL[tid] = lg;
      float pv = lg;
      if (!greedy) {
        const unsigned f = (unsigned)(b * NN + tid);
        unsigned x0 = 0u, x1 = f;
        tf2x32(keysL[2 * t], keysL[2 * t + 1], x0, x1);
        const unsigned bits = x0 ^ x1;
        const float fl = __uint_as_float((bits >> 9) | 0x3f800000u) - 1.0f;
        const float TINY = 1.17549435e-38f;
        float uu = fl + TINY;
        uu = fmaxf(TINY, uu);
        const float gum = -logf(-logf(uu));
        pv = lg + gum;
      }
      pertL[tid] = pv;
    }
    __syncthreads();
    // P5a: argmax (first-max) + logsumexp, wave 0
    if (tid < 64) {
      float v = (tid < NN) ? pertL[tid] : NINF;
      int bi = tid;
#pragma unroll
      for (int o = 32; o; o >>= 1) {
        const float v2 = __shfl_xor(v, o);
        const int i2 = __shfl_xor(bi, o);
        if (v2 > v || (v2 == v && i2 < bi)) { v = v2; bi = i2; }
      }
      float l = (tid < NN) ? logitsL[tid] : NINF;
      float m = l;
#pragma unroll
      for (int o = 32; o; o >>= 1) m = fmaxf(m, __shfl_xor(m, o));
      float e = expf(l - m);
#pragma unroll
      for (int o = 32; o; o >>= 1) e += __shfl_xor(e, o);
      if (tid == 0) {
        bestS = bi;
        lpS = (logitsL[bi] - m) - logf(e);
      }
    }
    __syncthreads();
    // P5b: state update (scalar)
    if (tid == 0) {
      const int best = bestS;
      float dyn = dynL;
      dyn = (best == 0) ? cap0 : (dyn - demL[best]);
      mask1L[best] = 1.f;
      float s1 = 0.f;
      for (int n = 1; n < NN; ++n) s1 += mask1L[n];
      float depot = (best == 0) ? 1.f : 0.f;
      if (s1 >= (float)(NN - 1)) depot = 0.f;
      mask1L[0] = depot;
      depotS = depot;
      float lp = lpS;
      if (s1 >= (float)NN) lp = 0.f;
      lpaccL += lp;
      dynL = dyn;
      idxL = best;
      out[b * ns + t] = (float)best;
    }
    __syncthreads();
    if (tid < NN)
      maskL[tid] = (tid == 0) ? depotS
                 : fminf(mask1L[tid] + ((demL[tid] > dynL) ? 1.f : 0.f), 1.f);
    __syncthreads();
  }
  if (tid == 0) out[Bn * ns + b] = lpaccL;
}

extern "C" void kernel_launch(void* const* d_in, const int* in_sizes, int n_in,
                              void* d_out, int out_size, void* d_ws, size_t ws_size,
                              hipStream_t stream) {
  const float* enc    = (const float*)d_in[0];
  const float* pool   = (const float*)d_in[1];
  const float* cap    = (const float*)d_in[2];
  const float* dem    = (const float*)d_in[3];
  const float* fc_w   = (const float*)d_in[4];
  const float* fc1_w  = (const float*)d_in[5];
  const float* wq     = (const float*)d_in[6];
  const float* wk     = (const float*)d_in[7];
  const float* wv     = (const float*)d_in[8];
  const float* wo     = (const float*)d_in[9];
  const float* wkp    = (const float*)d_in[10];
  const float* Tp     = (const float*)d_in[11];
  const int*   nsp    = (const int*)d_in[12];
  const int*   greedy = (const int*)d_in[14];
  float* out = (float*)d_out;

  const int B = in_sizes[1] / DD;  // pool is (B,128)

  hipLaunchKernelGGL(decode_kernel, dim3(B), dim3(256), 0, stream,
                     enc, pool, cap, dem, fc_w, fc1_w, wq, wk, wv, wo, wkp,
                     Tp, nsp, greedy, out);
}

// Round 3
// 327.974 us; speedup vs baseline: 1.2961x; 1.2961x over previous
//
#include <hip/hip_runtime.h>

#define NN 51
#define NR 52     // padded row count for V / attention rows
#define DD 128
#define RS 132    // row stride (words); 132/4=33 odd -> good b128 bank spread
#define NT 64

// JAX threefry2x32 (20 rounds), exact.
__device__ __forceinline__ void tf2x32(unsigned k0, unsigned k1, unsigned &x0, unsigned &x1) {
  const unsigned ks2 = k0 ^ k1 ^ 0x1BD11BDAu;
  const unsigned ka[5] = {k1, ks2, k0, k1, ks2};
  const unsigned kb[5] = {ks2 + 1u, k0 + 2u, k1 + 3u, ks2 + 4u, k0 + 5u};
  x0 += k0; x1 += k1;
#pragma unroll
  for (int g = 0; g < 5; ++g) {
    const int r0 = (g & 1) ? 17 : 13;
    const int r1 = (g & 1) ? 29 : 15;
    const int r2 = (g & 1) ? 16 : 26;
    const int r3 = (g & 1) ? 24 : 6;
    x0 += x1; x1 = (x1 << r0) | (x1 >> (32 - r0)); x1 ^= x0;
    x0 += x1; x1 = (x1 << r1) | (x1 >> (32 - r1)); x1 ^= x0;
    x0 += x1; x1 = (x1 << r2) | (x1 >> (32 - r2)); x1 ^= x0;
    x0 += x1; x1 = (x1 << r3) | (x1 >> (32 - r3)); x1 ^= x0;
    x0 += ka[g]; x1 += kb[g];
  }
}

__device__ __forceinline__ float dot4(const float4 a, const float4 b) {
  return a.x * b.x + a.y * b.y + a.z * b.z + a.w * b.w;
}

__global__ __launch_bounds__(256, 1) void decode_kernel(
    const float* __restrict__ enc, const float* __restrict__ pool_in,
    const float* __restrict__ cap_p, const float* __restrict__ demand,
    const float* __restrict__ fc_w, const float* __restrict__ fc1,
    const float* __restrict__ wq, const float* __restrict__ wk,
    const float* __restrict__ wv, const float* __restrict__ wo,
    const float* __restrict__ wkp, const float* __restrict__ T_p,
    const int* __restrict__ ns_p, const int* __restrict__ greedy_p,
    float* __restrict__ out) {
  __shared__ __align__(16) float Ksh[NN * RS];
  __shared__ __align__(16) float Vsh[NR * RS];     // row 51 zeroed
  __shared__ __align__(16) float KP2sh[NN * RS];   // T2=E@wkp -> KP2=T2@wo^T
  __shared__ __align__(16) float EQsh[NN * RS];    // T1=E@fc_top -> EQ=T1@wq
  __shared__ __align__(16) float qpoolL[NT * DD];  // first: staged enc; later qpool[t]
  __shared__ __align__(16) float uL[8 * NR];       // attn weights, col 51 zeroed
  __shared__ __align__(16) float qL[DD];
  __shared__ __align__(16) float gL[DD];
  __shared__ __align__(16) float poolL[DD];
  __shared__ __align__(16) float wrowL[DD];
  __shared__ __align__(16) float partF[256];
  __shared__ __align__(16) float partQ[256];
  __shared__ float logitsL[NN], pertL[NN], maskL[NN], mask1L[NN], demL[NN];
  __shared__ float pgumL[NR];
  __shared__ unsigned keysL[2 * NT];
  __shared__ float dynL, lpaccL, depotS;
  __shared__ int idxL, cntS;

  const int b = blockIdx.x, tid = threadIdx.x;
  const int Bn = gridDim.x;
  int ns = *ns_p; if (ns > NT) ns = NT;
  const int greedy = *greedy_p;
  const float Tval = *T_p;
  const float cap0 = *cap_p;
  const float NINF = -__builtin_inff();
  const float TINY = 1.17549435e-38f;

  // ---- stage: enc row (float4), demand, pool, state, threefry keys ----
  {
    const float4* src = (const float4*)(enc + (size_t)b * NN * DD);
    float4* dst = (float4*)qpoolL;
    for (int e = tid; e < NN * DD / 4; e += 256) dst[e] = src[e];
  }
  if (tid < 128) poolL[tid] = pool_in[b * DD + tid];
  if (tid < 132) Vsh[51 * RS + tid] = 0.f;   // zero pad row
  if (tid < NN)  { demL[tid] = demand[b * NN + tid]; mask1L[tid] = 0.f; }
  if (tid == 0)  { dynL = cap0; lpaccL = 0.f; idxL = 0; cntS = 0; depotS = 1.f; mask1L[0] = 1.f; }
  if (tid < ns) {  // fold_in(key(1234),0) then partitionable split child t
    unsigned a0 = 0u, a1 = 0u;
    tf2x32(0u, 1234u, a0, a1);
    unsigned x0 = 0u, x1 = (unsigned)tid;
    tf2x32(a0, a1, x0, x1);
    keysL[2 * tid] = x0; keysL[2 * tid + 1] = x1;
  }
  __syncthreads();

  const int g = tid >> 7, cc = tid & 127;
  const int n0 = g ? 26 : 0, cnt = g ? 25 : 26;

  // initial mask (idx=0, dyn=cap0, nothing visited)
  if (tid < NN)
    maskL[tid] = (tid == 0) ? 1.f : ((demL[tid] > cap0) ? 1.f : 0.f);
  // wrow[c] = fc_w[128,:] @ wq[:,c]
  if (tid < 128) {
    float s0 = 0.f, s1 = 0.f;
    for (int j = 0; j < DD; j += 2) {
      s0 += fc_w[128 * DD + j] * wq[j * DD + tid];
      s1 += fc_w[128 * DD + j + 1] * wq[(j + 1) * DD + tid];
    }
    wrowL[tid] = s0 + s1;
  }

  // ---- phase A: K=E@wk, V=E@wv, T1=E@fc_top, T2=E@wkp ----
  {
    const float* Wm[4] = {wk, wv, fc_w, wkp};
    float* Om[4] = {Ksh, Vsh, EQsh, KP2sh};
#pragma unroll
    for (int m = 0; m < 4; ++m) {
      const float* W = Wm[m];
      float acc[26];
#pragma unroll
      for (int r = 0; r < 26; ++r) acc[r] = 0.f;
      for (int i = 0; i < DD; i += 4) {
        const float w0 = W[(i + 0) * DD + cc];
        const float w1 = W[(i + 1) * DD + cc];
        const float w2 = W[(i + 2) * DD + cc];
        const float w3 = W[(i + 3) * DD + cc];
#pragma unroll
        for (int r = 0; r < 26; ++r) {
          if (r < cnt) {
            const float4 e4 = *(const float4*)&qpoolL[(n0 + r) * DD + i];
            acc[r] += e4.x * w0 + e4.y * w1 + e4.z * w2 + e4.w * w3;
          }
        }
      }
      float* O = Om[m];
#pragma unroll
      for (int r = 0; r < 26; ++r) if (r < cnt) O[(n0 + r) * RS + cc] = acc[r];
    }
  }
  __syncthreads();

  // ---- phase B1: EQ = T1 @ wq, in place ----
  {
    float acc[26];
#pragma unroll
    for (int r = 0; r < 26; ++r) acc[r] = 0.f;
    for (int i = 0; i < DD; i += 4) {
      const float w0 = wq[(i + 0) * DD + cc];
      const float w1 = wq[(i + 1) * DD + cc];
      const float w2 = wq[(i + 2) * DD + cc];
      const float w3 = wq[(i + 3) * DD + cc];
#pragma unroll
      for (int r = 0; r < 26; ++r) {
        if (r < cnt) {
          const float4 e4 = *(const float4*)&EQsh[(n0 + r) * RS + i];
          acc[r] += e4.x * w0 + e4.y * w1 + e4.z * w2 + e4.w * w3;
        }
      }
    }
    __syncthreads();
#pragma unroll
    for (int r = 0; r < 26; ++r) if (r < cnt) EQsh[(n0 + r) * RS + cc] = acc[r];
  }
  __syncthreads();

  // ---- phase B2: KP2 = T2 @ wo^T, in place ----
  {
    float acc[26];
#pragma unroll
    for (int r = 0; r < 26; ++r) acc[r] = 0.f;
    for (int d = 0; d < DD; d += 4) {
      const float4 w4 = *(const float4*)&wo[cc * DD + d];
#pragma unroll
      for (int r = 0; r < 26; ++r) {
        if (r < cnt) {
          const float4 t4 = *(const float4*)&KP2sh[(n0 + r) * RS + d];
          acc[r] += t4.x * w4.x + t4.y * w4.y + t4.z * w4.z + t4.w * w4.w;
        }
      }
    }
    __syncthreads();
#pragma unroll
    for (int r = 0; r < 26; ++r) if (r < cnt) KP2sh[(n0 + r) * RS + cc] = acc[r];
  }
  __syncthreads();

  // ---- phase C: pool chain; qpool[t] = pool_{t+1} @ wq (2 barriers/iter) ----
  {
    const int i0 = g << 6;
    float wf[64], wqr[64];
#pragma unroll
    for (int i = 0; i < 64; ++i) {
      wf[i]  = fc1[(i0 + i) * DD + cc];
      wqr[i] = wq[(i0 + i) * DD + cc];
    }
    float sf = 0.f;
#pragma unroll
    for (int i = 0; i < 64; ++i) sf += poolL[i0 + i] * wf[i];
    partF[tid] = sf;
    __syncthreads();
    if (tid < 128) poolL[tid] = partF[tid] + partF[tid + 128];  // pool_1
    __syncthreads();
    for (int t = 0; t < ns; ++t) {
      float sq = 0.f, sfn = 0.f;
#pragma unroll
      for (int i = 0; i < 64; ++i) {
        const float p = poolL[i0 + i];
        sq  += p * wqr[i];
        sfn += p * wf[i];
      }
      partQ[tid] = sq; partF[tid] = sfn;
      __syncthreads();
      if (tid < 128) {
        qpoolL[t * DD + tid] = partQ[tid] + partQ[tid + 128];
        if (t + 1 < ns) poolL[tid] = partF[tid] + partF[tid + 128];
      }
      __syncthreads();
    }
  }

  // ---- pre-loop: qL for t=0, gumbel for t=0 ----
  if (tid < 128)
    qL[tid] = EQsh[tid] + cap0 * wrowL[tid] + qpoolL[tid];  // idx=0
  if (!greedy && (tid >> 6) == 3) {
    const int l = tid & 63;
    if (l < NN) {
      unsigned x0 = 0u, x1 = (unsigned)(b * NN + l);
      tf2x32(keysL[0], keysL[1], x0, x1);
      const unsigned bits = x0 ^ x1;
      const float fl = __uint_as_float((bits >> 9) | 0x3f800000u) - 1.0f;
      const float uu = fmaxf(TINY, fl + TINY);
      pgumL[l] = -logf(-logf(uu));
    }
  }
  __syncthreads();

  // ---- sequential decode: 3 barriers/step ----
  for (int t = 0; t < ns; ++t) {
    // P123: per wave w -> heads 2w,2w+1 ; QK dot + softmax + PV, intra-wave only
    {
      const int w = tid >> 6, l = tid & 63;
      const int h = 2 * w + (l >> 5), j = l & 31;
      const float4* qr = (const float4*)&qL[h * 16];
      const float4 q0 = qr[0], q1 = qr[1], q2 = qr[2], q3 = qr[3];
      float u1, u2 = NINF;
      {
        const float4* kr = (const float4*)&Ksh[j * RS + h * 16];
        const float s = (dot4(kr[0], q0) + dot4(kr[1], q1)) +
                        (dot4(kr[2], q2) + dot4(kr[3], q3));
        u1 = (maskL[j] > 0.f) ? NINF : 0.25f * s;
      }
      if (j < 19) {
        const float4* kr = (const float4*)&Ksh[(j + 32) * RS + h * 16];
        const float s = (dot4(kr[0], q0) + dot4(kr[1], q1)) +
                        (dot4(kr[2], q2) + dot4(kr[3], q3));
        u2 = (maskL[j + 32] > 0.f) ? NINF : 0.25f * s;
      }
      float m = fmaxf(u1, u2);
#pragma unroll
      for (int o = 16; o; o >>= 1) m = fmaxf(m, __shfl_xor(m, o, 32));
      const float e1 = expf(u1 - m);
      const float e2 = (j < 19) ? expf(u2 - m) : 0.f;
      float ssum = e1 + e2;
#pragma unroll
      for (int o = 16; o; o >>= 1) ssum += __shfl_xor(ssum, o, 32);
      uL[h * NR + j] = e1 / ssum;
      if (j < 19) uL[h * NR + j + 32] = e2 / ssum;
      if (j == 19) uL[h * NR + 51] = 0.f;
      asm volatile("s_waitcnt lgkmcnt(0)" ::: "memory");
      // PV: lane j -> d = h*16+(j&15), n-half = j>>4 (26 rows each, row 51 zero)
      const int dh = j & 15, jh = j >> 4;
      const int d = h * 16 + dh;
      const int nA = jh * 26;
      const int u0 = h * NR + nA;
      float b0 = 0.f, b1 = 0.f;
#pragma unroll
      for (int r = 0; r < 26; r += 2) {
        b0 += uL[u0 + r]     * Vsh[(nA + r) * RS + d];
        b1 += uL[u0 + r + 1] * Vsh[(nA + r + 1) * RS + d];
      }
      float gsum = b0 + b1;
      gsum += __shfl_xor(gsum, 16, 32);
      if (jh == 0) gL[d] = gsum;
    }
    __syncthreads();
    // P4: comp -> logits -> perturbed (4 lanes per node)
    if (tid < 4 * NN) {
      const int n = tid >> 2, jq = tid & 3;
      const float4* kp = (const float4*)&KP2sh[n * RS + jq * 32];
      const float4* gg = (const float4*)&gL[jq * 32];
      float a0 = 0.f, a1 = 0.f;
#pragma unroll
      for (int i = 0; i < 8; i += 2) {
        a0 += dot4(kp[i], gg[i]);
        a1 += dot4(kp[i + 1], gg[i + 1]);
      }
      float s = a0 + a1;
      s += __shfl_xor(s, 1, 4);
      s += __shfl_xor(s, 2, 4);
      if (jq == 0) {
        const float comp = s * 0.08838834764831845f;  // 128^-0.5
        float lg = (10.f * tanhf(comp)) / Tval;
        lg = (maskL[n] > 0.f) ? NINF : lg;
        logitsL[n] = lg;
        pertL[n] = greedy ? lg : (lg + pgumL[n]);
      }
    }
    __syncthreads();
    // P5: wave0 argmax+LSE+state+mask+next-q ; wave3 gumbel for t+1
    {
      const int w = tid >> 6, l = tid & 63;
      if (w == 0) {
        float v = (l < NN) ? pertL[l] : NINF;
        int bi = l;
#pragma unroll
        for (int o = 32; o; o >>= 1) {
          const float v2 = __shfl_xor(v, o);
          const int i2 = __shfl_xor(bi, o);
          if (v2 > v || (v2 == v && i2 < bi)) { v = v2; bi = i2; }
        }
        float lgv = (l < NN) ? logitsL[l] : NINF;
        float mm = lgv;
#pragma unroll
        for (int o = 32; o; o >>= 1) mm = fmaxf(mm, __shfl_xor(mm, o));
        float ee = expf(lgv - mm);
#pragma unroll
        for (int o = 32; o; o >>= 1) ee += __shfl_xor(ee, o);
        if (l == 0) {
          const int best = bi;
          const float dyn = (best == 0) ? cap0 : (dynL - demL[best]);
          int c2 = cntS;
          if (best != 0 && mask1L[best] == 0.f) c2++;
          mask1L[best] = 1.f;
          float depot = (best == 0) ? 1.f : 0.f;
          if (c2 >= NN - 1) depot = 0.f;
          mask1L[0] = depot;
          depotS = depot;
          cntS = c2;
          dynL = dyn;
          idxL = best;
          lpaccL += (logitsL[best] - mm) - logf(ee);
          out[b * ns + t] = (float)best;
        }
        asm volatile("s_waitcnt lgkmcnt(0)" ::: "memory");
        if (l < NN)
          maskL[l] = (l == 0) ? depotS
                   : fminf(mask1L[l] + ((demL[l] > dynL) ? 1.f : 0.f), 1.f);
        // next step's q (qpool slot t+1; slot ns is deterministic garbage, unused)
        {
          const int ix = idxL;
          const float dd = dynL;
          qL[l]      = EQsh[ix * RS + l]      + dd * wrowL[l]      + qpoolL[(t + 1) * DD + l];
          qL[l + 64] = EQsh[ix * RS + l + 64] + dd * wrowL[l + 64] + qpoolL[(t + 1) * DD + l + 64];
        }
      } else if (w == 3 && !greedy) {
        if (l < NN && t + 1 < ns) {
          unsigned x0 = 0u, x1 = (unsigned)(b * NN + l);
          tf2x32(keysL[2 * (t + 1)], keysL[2 * (t + 1) + 1], x0, x1);
          const unsigned bits = x0 ^ x1;
          const float fl = __uint_as_float((bits >> 9) | 0x3f800000u) - 1.0f;
          const float uu = fmaxf(TINY, fl + TINY);
          pgumL[l] = -logf(-logf(uu));
        }
      }
    }
    __syncthreads();
  }
  if (tid == 0) out[Bn * ns + b] = lpaccL;
}

extern "C" void kernel_launch(void* const* d_in, const int* in_sizes, int n_in,
                              void* d_out, int out_size, void* d_ws, size_t ws_size,
                              hipStream_t stream) {
  const float* enc    = (const float*)d_in[0];
  const float* pool   = (const float*)d_in[1];
  const float* cap    = (const float*)d_in[2];
  const float* dem    = (const float*)d_in[3];
  const float* fc_w   = (const float*)d_in[4];
  const float* fc1_w  = (const float*)d_in[5];
  const float* wq     = (const float*)d_in[6];
  const float* wk     = (const float*)d_in[7];
  const float* wv     = (const float*)d_in[8];
  const float* wo     = (const float*)d_in[9];
  const float* wkp    = (const float*)d_in[10];
  const float* Tp     = (const float*)d_in[11];
  const int*   nsp    = (const int*)d_in[12];
  const int*   greedy = (const int*)d_in[14];
  float* out = (float*)d_out;

  const int B = in_sizes[1] / DD;  // pool is (B,128)

  hipLaunchKernelGGL(decode_kernel, dim3(B), dim3(256), 0, stream,
                     enc, pool, cap, dem, fc_w, fc1_w, wq, wk, wv, wo, wkp,
                     Tp, nsp, greedy, out);
}